// Round 3
// baseline (78037.286 us; speedup 1.0000x reference)
//
#include <hip/hip_runtime.h>
#include <hip/hip_bf16.h>

// ============================================================================
// 2-layer quirky LSTM, persistent kernel, round 3.
// Precision: the c-recurrence is marginally chaotic (gain sig(c)+c*sig'(c)>1
// for c in ~[1.7,8]) -> per-step gate noise must be ~f32-level. ALL MFMA
// inputs are double-bf16 (hi+lo): W (precomputed), h (stored hi+lo planes),
// x (converted on the fly from f32). gates = Whi*ahi + Whi*alo + Wlo*ahi.
// Structure: 256 WGs x 256 thr (1/CU). Per layer 128 WGs = 2 Mg(64 rows) x
// 64 jt(16 j-units x 3 gates). Each wave: 16 rows x full K, no LDS reduction.
// Phase p: L0 computes t=p || L1 computes t=p-1; grid barrier between phases.
// h crosses XCDs via agent-scope atomics (LLC), ping-pong 2-deep.
// ============================================================================

typedef __attribute__((ext_vector_type(8))) short bf16x8;
typedef __attribute__((ext_vector_type(4))) float f32x4;
#define DEV __device__ __forceinline__

namespace {
constexpr int Bb = 128, Ss = 1024, Ii = 512, Hh = 1024;
constexpr int K0 = Ii + Hh;            // 1536
constexpr int K1 = 2 * Hh;             // 2048
constexpr int NWG = 256;
constexpr int NPH = Ss + 1;

constexpr size_t BH    = (size_t)Bb * Hh;
constexpr size_t OF_H0 = (size_t)Bb * Ss * Hh;
constexpr size_t OF_C0 = OF_H0 + BH;
constexpr size_t OF_H1 = OF_C0 + BH;
constexpr size_t OF_C1 = OF_H1 + BH;

// workspace
constexpr size_t WS_GO    = 0;
constexpr size_t WS_SLOTS = 256;                    // 256 ints
constexpr size_t WS_C0    = 4096;                   // f32 [B][H]
constexpr size_t WS_C1    = WS_C0 + BH * 4;
constexpr size_t WS_H0HI  = WS_C1 + BH * 4;         // bf16 [2][B][H] ping-pong
constexpr size_t WS_H0LO  = WS_H0HI + 2 * BH * 2;
constexpr size_t WS_H1HI  = WS_H0LO + 2 * BH * 2;
constexpr size_t WS_H1LO  = WS_H1HI + 2 * BH * 2;
constexpr size_t WS_ZEND  = WS_H1LO + 2 * BH * 2;   // ~3.1 MB zeroed per launch
constexpr size_t WSZ_W0   = (size_t)3 * Hh * K0 * 2;
constexpr size_t WSZ_W1   = (size_t)3 * Hh * K1 * 2;
constexpr size_t WS_W0H   = WS_ZEND;                // hi planes first
constexpr size_t WS_W1H   = WS_W0H + WSZ_W0;
constexpr size_t WS_W0L   = WS_W1H + WSZ_W1;        // lo planes after
constexpr size_t WS_W1L   = WS_W0L + WSZ_W0;
constexpr size_t WS_NEED  = WS_W1L + WSZ_W1;        // ~47.2 MB
constexpr size_t WS_HIEND = WS_W0L;                 // ~25.2 MB (hi-only fallback)
}

DEV unsigned short bf16r(float f) {
  return __builtin_bit_cast(unsigned short, __float2bfloat16(f));
}
DEV float bf2f(unsigned short u) {
  unsigned int x = (unsigned int)u << 16;
  return __builtin_bit_cast(float, x);
}
DEV float sig_(float x) { return 1.f / (1.f + __expf(-x)); }
DEV float tanh_(float x) {
  float e = __expf(-2.f * fabsf(x));
  return copysignf((1.f - e) / (1.f + e), x);
}
DEV bf16x8 ld16(const unsigned short* p) { return *reinterpret_cast<const bf16x8*>(p); }
DEV bf16x8 ldcoh(const unsigned short* p) {   // agent-scope 16B (2x8B) load
  union { unsigned long long u[2]; bf16x8 v; } t;
  t.u[0] = __hip_atomic_load((const unsigned long long*)p,     __ATOMIC_RELAXED, __HIP_MEMORY_SCOPE_AGENT);
  t.u[1] = __hip_atomic_load((const unsigned long long*)p + 1, __ATOMIC_RELAXED, __HIP_MEMORY_SCOPE_AGENT);
  return t.v;
}
#define MFMA __builtin_amdgcn_mfma_f32_16x16x32_bf16

// ---------------------------------------------------------------------------
__global__ void k_zero(uint4* p, int n16) {
  for (int i = blockIdx.x * blockDim.x + threadIdx.x; i < n16; i += gridDim.x * blockDim.x)
    p[i] = make_uint4(0u, 0u, 0u, 0u);
}

template <bool WLO>
__global__ void k_convert(const float* __restrict__ W0, const float* __restrict__ W1,
                          unsigned short* __restrict__ w0h, unsigned short* __restrict__ w0l,
                          unsigned short* __restrict__ w1h, unsigned short* __restrict__ w1l) {
  const long NW04 = (long)3 * Hh * K0 / 4;
  const long NW14 = (long)3 * Hh * K1 / 4;
  const long total = NW04 + NW14;
  for (long i = (long)blockIdx.x * blockDim.x + threadIdx.x; i < total;
       i += (long)gridDim.x * blockDim.x) {
    long e; const float* src; unsigned short *dh, *dl;
    if (i < NW04) { e = i * 4;          src = W0 + e; dh = w0h + e; dl = w0l + e; }
    else          { e = (i - NW04) * 4; src = W1 + e; dh = w1h + e; dl = w1l + e; }
    f32x4 v = *(const f32x4*)src;
    unsigned long long ph = 0, pl = 0;
#pragma unroll
    for (int e2 = 0; e2 < 4; ++e2) {
      unsigned short hi = bf16r(v[e2]);
      ph |= (unsigned long long)hi << (16 * e2);
      if (WLO) pl |= (unsigned long long)bf16r(v[e2] - bf2f(hi)) << (16 * e2);
    }
    *(unsigned long long*)dh = ph;
    if (WLO) *(unsigned long long*)dl = pl;
  }
}

// ---------------------------------------------------------------------------
// 9 (WLO) / 6 (!WLO) MFMAs per 32-k chunk per gate-triple, named accumulators.
#define GSTEP(ahi, alo, ko, I, G, O)                                  \
  do {                                                                \
    I = MFMA(ld16(whi + off0 + (ko)), (ahi), I, 0, 0, 0);             \
    G = MFMA(ld16(whi + off1 + (ko)), (ahi), G, 0, 0, 0);             \
    O = MFMA(ld16(whi + off2 + (ko)), (ahi), O, 0, 0, 0);             \
    if (WLO) {                                                        \
      I = MFMA(ld16(wlo + off0 + (ko)), (ahi), I, 0, 0, 0);           \
      G = MFMA(ld16(wlo + off1 + (ko)), (ahi), G, 0, 0, 0);           \
      O = MFMA(ld16(wlo + off2 + (ko)), (ahi), O, 0, 0, 0);           \
    }                                                                 \
    I = MFMA(ld16(whi + off0 + (ko)), (alo), I, 0, 0, 0);             \
    G = MFMA(ld16(whi + off1 + (ko)), (alo), G, 0, 0, 0);             \
    O = MFMA(ld16(whi + off2 + (ko)), (alo), O, 0, 0, 0);             \
  } while (0)

#define HSTEP(hiP, loP, ka, ko, I, G, O)                              \
  do {                                                                \
    bf16x8 ahi_ = ldcoh((hiP) + (ka));                                \
    bf16x8 alo_ = ldcoh((loP) + (ka));                                \
    GSTEP(ahi_, alo_, (ko), I, G, O);                                 \
  } while (0)

template <bool WLO>
__global__ __launch_bounds__(256, 1) void lstm_persist(
    const float* __restrict__ xf,
    const float* __restrict__ fw, const float* __restrict__ tw, const float* __restrict__ mag,
    const unsigned short* __restrict__ w0h, const unsigned short* __restrict__ w0l,
    const float* __restrict__ b0,
    const unsigned short* __restrict__ w1h, const unsigned short* __restrict__ w1l,
    const float* __restrict__ b1,
    float* __restrict__ out,
    unsigned short* __restrict__ h0hi, unsigned short* __restrict__ h0lo,
    unsigned short* __restrict__ h1hi, unsigned short* __restrict__ h1lo,
    float* __restrict__ c0, float* __restrict__ c1,
    int* __restrict__ slots, int* __restrict__ go) {
  const int tid = threadIdx.x;
  const int lane = tid & 63;
  const int wv = tid >> 6;               // 0..3 : M-subtile (16 rows each)
  const int l15 = lane & 15, l4 = lane >> 4;

  const int wg = blockIdx.x;
  const int layer = wg >> 7;             // 0..127 -> L0, 128..255 -> L1
  const int i = wg & 127;
  const int x8 = i & 7, kk = i >> 3;     // same-XCD (empirically wg%8) WGs share jt range
  const int jt = x8 * 8 + (kk >> 1);     // 0..63
  const int mg = kk & 1;                 // M-group (64 rows)
  const int jb = jt * 16;

  const int bact = mg * 64 + wv * 16 + l15;   // batch row
  const int j0 = jb + l4 * 4;                 // 4 hidden units per lane

  const int K = layer ? K1 : K0;
  const unsigned short* whi = layer ? w1h : w0h;
  const unsigned short* wlo = layer ? w1l : w0l;
  const size_t off0 = (size_t)(0 * Hh + jb + l15) * K + l4 * 8;
  const size_t off1 = (size_t)(1 * Hh + jb + l15) * K + l4 * 8;
  const size_t off2 = (size_t)(2 * Hh + jb + l15) * K + l4 * 8;

  const float* bb = layer ? b1 : b0;
  const f32x4 bi = *(const f32x4*)(bb + j0);
  const f32x4 bg = *(const f32x4*)(bb + Hh + j0);
  const f32x4 bo = *(const f32x4*)(bb + 2 * Hh + j0);

  float* cst = (layer ? c1 : c0) + (size_t)bact * Hh + j0;
  float* outb = out + (size_t)bact * Ss * Hh + j0;
  const float emag = __expf(mag[0]);

  for (int p = 0; p < NPH; ++p) {
    const bool act = layer ? (p >= 1) : (p < Ss);
    const int t = layer ? (p - 1) : p;

    if (act) {
      f32x4 z = {0.f, 0.f, 0.f, 0.f};
      f32x4 aI0 = z, aG0 = z, aO0 = z, aI1 = z, aG1 = z, aO1 = z;

      const size_t hbase = (size_t)((p + 1) & 1) * BH + (size_t)bact * Hh + l4 * 8;
      if (layer == 0) {
        // ---- x part: k = 0..511, on-the-fly double-bf16 from f32 ----
        const float* px = xf + ((size_t)bact * Ss + t) * Ii + l4 * 8;
        const float twm = tw[t] * emag;
#pragma unroll 2
        for (int c = 0; c < 16; ++c) {
          const int k = c * 32;
          f32x4 x0 = *(const f32x4*)(px + k);
          f32x4 x1 = *(const f32x4*)(px + k + 4);
          f32x4 f0 = *(const f32x4*)(fw + k + l4 * 8);
          f32x4 f1 = *(const f32x4*)(fw + k + l4 * 8 + 4);
          x0 *= f0 * twm; x1 *= f1 * twm;
          bf16x8 ahi, alo;
#pragma unroll
          for (int e = 0; e < 4; ++e) {
            unsigned short h0_ = bf16r(x0[e]), h1_ = bf16r(x1[e]);
            ahi[e] = (short)h0_; ahi[e + 4] = (short)h1_;
            alo[e] = (short)bf16r(x0[e] - bf2f(h0_));
            alo[e + 4] = (short)bf16r(x1[e] - bf2f(h1_));
          }
          if (c & 1) GSTEP(ahi, alo, k, aI1, aG1, aO1);
          else       GSTEP(ahi, alo, k, aI0, aG0, aO0);
        }
        // ---- h0_prev part: k = 512..1535 ----
        const unsigned short* hp = h0hi + hbase;
        const unsigned short* lp = h0lo + hbase;
#pragma unroll 2
        for (int c = 0; c < 32; c += 2) {
          HSTEP(hp, lp, c * 32,       Ii + c * 32,       aI0, aG0, aO0);
          HSTEP(hp, lp, (c + 1) * 32, Ii + (c + 1) * 32, aI1, aG1, aO1);
        }
      } else {
        // ---- h0_t part: k = 0..1023 ----
        const unsigned short* hp = h0hi + hbase;
        const unsigned short* lp = h0lo + hbase;
#pragma unroll 2
        for (int c = 0; c < 32; c += 2) {
          HSTEP(hp, lp, c * 32,       c * 32,       aI0, aG0, aO0);
          HSTEP(hp, lp, (c + 1) * 32, (c + 1) * 32, aI1, aG1, aO1);
        }
        // ---- h1_prev part: k = 1024..2047 ----
        const unsigned short* hp1 = h1hi + hbase;
        const unsigned short* lp1 = h1lo + hbase;
#pragma unroll 2
        for (int c = 0; c < 32; c += 2) {
          HSTEP(hp1, lp1, c * 32,       Hh + c * 32,       aI0, aG0, aO0);
          HSTEP(hp1, lp1, (c + 1) * 32, Hh + (c + 1) * 32, aI1, aG1, aO1);
        }
      }

      f32x4 ai = aI0 + aI1 + bi;
      f32x4 ag = aG0 + aG1 + bg;
      f32x4 ao = aO0 + aO1 + bo;
      f32x4 cp = *(const f32x4*)cst;
      f32x4 cn, hn;
      unsigned long long hpk = 0, lpk = 0;
#pragma unroll
      for (int r = 0; r < 4; ++r) {
        float f = sig_(cp[r]);                     // forget gate from c_prev (quirk)
        float cc = f * cp[r] + sig_(ai[r]) * tanh_(ag[r]);
        float hh = sig_(ao[r]) * tanh_(cc) * f;    // extra *f (quirk)
        cn[r] = cc; hn[r] = hh;
        unsigned short hi = bf16r(hh);
        hpk |= (unsigned long long)hi << (16 * r);
        lpk |= (unsigned long long)bf16r(hh - bf2f(hi)) << (16 * r);
      }
      *(f32x4*)cst = cn;
      const size_t wbase = (size_t)(p & 1) * BH + (size_t)bact * Hh + j0;
      unsigned short* whp = (layer ? h1hi : h0hi) + wbase;
      unsigned short* wlp = (layer ? h1lo : h0lo) + wbase;
      __hip_atomic_store((unsigned long long*)whp, hpk, __ATOMIC_RELAXED, __HIP_MEMORY_SCOPE_AGENT);
      __hip_atomic_store((unsigned long long*)wlp, lpk, __ATOMIC_RELAXED, __HIP_MEMORY_SCOPE_AGENT);
      if (layer) {
        *(f32x4*)(outb + (size_t)t * Hh) = hn;
        if (t == Ss - 1) {
          *(f32x4*)(out + OF_H1 + (size_t)bact * Hh + j0) = hn;
          *(f32x4*)(out + OF_C1 + (size_t)bact * Hh + j0) = cn;
        }
      } else if (t == Ss - 1) {
        *(f32x4*)(out + OF_H0 + (size_t)bact * Hh + j0) = hn;
        *(f32x4*)(out + OF_C0 + (size_t)bact * Hh + j0) = cn;
      }
    }

    // ---- grid barrier (skip after final phase) ----
    if (p < NPH - 1) {
      __syncthreads();   // all waves done; vmcnt drained (stores at coherence point)
      if (wg == 0) {
        if (tid == 0)
          __hip_atomic_store(&slots[0], p + 1, __ATOMIC_RELAXED, __HIP_MEMORY_SCOPE_AGENT);
        int gd = 0; bool ok;
        do {
          int a = __hip_atomic_load(&slots[tid], __ATOMIC_RELAXED, __HIP_MEMORY_SCOPE_AGENT);
          ok = (a > p);
          if (!ok) __builtin_amdgcn_s_sleep(1);
        } while (!__syncthreads_and(ok) && ++gd < (1 << 22));
        if (tid == 0)
          __hip_atomic_store(go, p + 1, __ATOMIC_RELAXED, __HIP_MEMORY_SCOPE_AGENT);
      } else {
        if (tid == 0) {
          __hip_atomic_store(&slots[wg], p + 1, __ATOMIC_RELAXED, __HIP_MEMORY_SCOPE_AGENT);
          int gd = 0;
          while (__hip_atomic_load(go, __ATOMIC_RELAXED, __HIP_MEMORY_SCOPE_AGENT) <= p &&
                 ++gd < (1 << 24))
            __builtin_amdgcn_s_sleep(1);
        }
        __syncthreads();
      }
    }
  }
}

// ---------------------------------------------------------------------------
extern "C" void kernel_launch(void* const* d_in, const int* in_sizes, int n_in,
                              void* d_out, int out_size, void* d_ws, size_t ws_size,
                              hipStream_t stream) {
  const float* x   = (const float*)d_in[0];
  const float* fw  = (const float*)d_in[1];
  const float* tw  = (const float*)d_in[2];
  const float* mag = (const float*)d_in[3];
  const float* W0  = (const float*)d_in[4];
  const float* b0  = (const float*)d_in[5];
  const float* W1  = (const float*)d_in[6];
  const float* b1  = (const float*)d_in[7];
  float* out = (float*)d_out;
  char* ws = (char*)d_ws;

  if (ws_size < WS_HIEND) return;
  const bool wlo = ws_size >= WS_NEED;

  unsigned short* w0h = (unsigned short*)(ws + WS_W0H);
  unsigned short* w1h = (unsigned short*)(ws + WS_W1H);
  unsigned short* w0l = (unsigned short*)(ws + (wlo ? WS_W0L : WS_W0H));
  unsigned short* w1l = (unsigned short*)(ws + (wlo ? WS_W1L : WS_W1H));

  k_zero<<<770, 256, 0, stream>>>((uint4*)ws, (int)(WS_ZEND / 16));
  if (wlo)
    k_convert<true><<<1024, 256, 0, stream>>>(W0, W1, w0h, w0l, w1h, w1l);
  else
    k_convert<false><<<1024, 256, 0, stream>>>(W0, W1, w0h, w0l, w1h, w1l);

#define ARGS x, fw, tw, mag, w0h, w0l, b0, w1h, w1l, b1, out,                 \
    (unsigned short*)(ws + WS_H0HI), (unsigned short*)(ws + WS_H0LO),         \
    (unsigned short*)(ws + WS_H1HI), (unsigned short*)(ws + WS_H1LO),         \
    (float*)(ws + WS_C0), (float*)(ws + WS_C1),                               \
    (int*)(ws + WS_SLOTS), (int*)(ws + WS_GO)
  if (wlo)
    lstm_persist<true><<<NWG, 256, 0, stream>>>(ARGS);
  else
    lstm_persist<false><<<NWG, 256, 0, stream>>>(ARGS);
#undef ARGS
}

// Round 4
// 59286.774 us; speedup vs baseline: 1.3163x; 1.3163x over previous
//
#include <hip/hip_runtime.h>
#include <hip/hip_bf16.h>

// ============================================================================
// 2-layer quirky LSTM, persistent kernel, round 4.
// Numerics (validated r3): double-bf16 (hi+lo) for W, h, x; f32 c; ~1e-5 gate
// noise -> 0.0078 final error (68x margin).
// Perf fix this round (r3 = 78ms, FETCH 27MB/phase = W thrashing L2):
//  - W-lo resident in LDS (144KB/WG prologue; L1 K-tail streamed from L2)
//  - W-hi L2-resident (per-XCD slice 2.75+0.39MB < 4MB)
//  - 512-thr WGs: 8 waves = 4 row-subtiles x 2 K-halves + LDS reduction
//  - XOR swizzle (byte ^ (row&7)<<4) on LDS W-lo to kill bank conflicts
// ============================================================================

typedef __attribute__((ext_vector_type(8))) short bf16x8;
typedef __attribute__((ext_vector_type(4))) float f32x4;
typedef unsigned long long u64;
#define DEV __device__ __forceinline__

namespace {
constexpr int Bb = 128, Ss = 1024, Ii = 512, Hh = 1024;
constexpr int K0 = Ii + Hh;            // 1536
constexpr int K1 = 2 * Hh;             // 2048
constexpr int NWG = 256;               // 1 WG/CU, 512 threads
constexpr int NPH = Ss + 1;

constexpr size_t BH    = (size_t)Bb * Hh;
constexpr size_t OF_H0 = (size_t)Bb * Ss * Hh;
constexpr size_t OF_C0 = OF_H0 + BH;
constexpr size_t OF_H1 = OF_C0 + BH;
constexpr size_t OF_C1 = OF_H1 + BH;

// workspace (layout identical to round 3)
constexpr size_t WS_GO    = 0;
constexpr size_t WS_SLOTS = 256;
constexpr size_t WS_C0    = 4096;
constexpr size_t WS_C1    = WS_C0 + BH * 4;
constexpr size_t WS_H0HI  = WS_C1 + BH * 4;
constexpr size_t WS_H0LO  = WS_H0HI + 2 * BH * 2;
constexpr size_t WS_H1HI  = WS_H0LO + 2 * BH * 2;
constexpr size_t WS_H1LO  = WS_H1HI + 2 * BH * 2;
constexpr size_t WS_ZEND  = WS_H1LO + 2 * BH * 2;
constexpr size_t WSZ_W0   = (size_t)3 * Hh * K0 * 2;
constexpr size_t WSZ_W1   = (size_t)3 * Hh * K1 * 2;
constexpr size_t WS_W0H   = WS_ZEND;
constexpr size_t WS_W1H   = WS_W0H + WSZ_W0;
constexpr size_t WS_W0L   = WS_W1H + WSZ_W1;
constexpr size_t WS_W1L   = WS_W0L + WSZ_W0;
constexpr size_t WS_NEED  = WS_W1L + WSZ_W1;    // ~47.2 MB
constexpr size_t WS_HIEND = WS_W0L;             // hi-only fallback

// LDS: W-lo slice [48 rows][1536 bf16] swizzled, then reduction buffer
constexpr int LO_K     = 1536;                  // K-range of LDS lo slice
constexpr int LO_ROWB  = LO_K * 2;              // 3072 B per row
constexpr int LO_BYTES = 48 * LO_ROWB;          // 147456
constexpr int RED_BYTES = 4 * 3 * 64 * 16;      // mt x gate x lane f32x4 = 12288
constexpr int DYN_LDS  = LO_BYTES + RED_BYTES;  // 159744 <= 160 KiB
}

DEV unsigned short bf16r(float f) {
  return __builtin_bit_cast(unsigned short, __float2bfloat16(f));
}
DEV float bf2f(unsigned short u) {
  unsigned int x = (unsigned int)u << 16;
  return __builtin_bit_cast(float, x);
}
DEV float sig_(float x) { return 1.f / (1.f + __expf(-x)); }
DEV float tanh_(float x) {
  float e = __expf(-2.f * fabsf(x));
  return copysignf((1.f - e) / (1.f + e), x);
}
DEV bf16x8 ld16(const unsigned short* p) { return *reinterpret_cast<const bf16x8*>(p); }
DEV bf16x8 ldcoh(const unsigned short* p) {   // agent-scope 16B (2x8B) load
  union { u64 u[2]; bf16x8 v; } t;
  t.u[0] = __hip_atomic_load((const u64*)p,     __ATOMIC_RELAXED, __HIP_MEMORY_SCOPE_AGENT);
  t.u[1] = __hip_atomic_load((const u64*)p + 1, __ATOMIC_RELAXED, __HIP_MEMORY_SCOPE_AGENT);
  return t.v;
}
#define MFMA __builtin_amdgcn_mfma_f32_16x16x32_bf16

// ---------------------------------------------------------------------------
__global__ void k_zero(uint4* p, int n16) {
  for (int i = blockIdx.x * blockDim.x + threadIdx.x; i < n16; i += gridDim.x * blockDim.x)
    p[i] = make_uint4(0u, 0u, 0u, 0u);
}

template <bool WLO>
__global__ void k_convert(const float* __restrict__ W0, const float* __restrict__ W1,
                          unsigned short* __restrict__ w0h, unsigned short* __restrict__ w0l,
                          unsigned short* __restrict__ w1h, unsigned short* __restrict__ w1l) {
  const long NW04 = (long)3 * Hh * K0 / 4;
  const long NW14 = (long)3 * Hh * K1 / 4;
  const long total = NW04 + NW14;
  for (long i = (long)blockIdx.x * blockDim.x + threadIdx.x; i < total;
       i += (long)gridDim.x * blockDim.x) {
    long e; const float* src; unsigned short *dh, *dl;
    if (i < NW04) { e = i * 4;          src = W0 + e; dh = w0h + e; dl = w0l + e; }
    else          { e = (i - NW04) * 4; src = W1 + e; dh = w1h + e; dl = w1l + e; }
    f32x4 v = *(const f32x4*)src;
    u64 ph = 0, pl = 0;
#pragma unroll
    for (int e2 = 0; e2 < 4; ++e2) {
      unsigned short hi = bf16r(v[e2]);
      ph |= (u64)hi << (16 * e2);
      if (WLO) pl |= (u64)bf16r(v[e2] - bf2f(hi)) << (16 * e2);
    }
    *(u64*)dh = ph;
    if (WLO) *(u64*)dl = pl;
  }
}

// ---------------------------------------------------------------------------
// lo fragment from LDS (XOR-swizzled); kl = W K-index (< LO_K)
#define LD_LO(g, kl)                                                          \
  (*(const bf16x8*)(lds + ((g) * 16 + l15) * LO_ROWB +                        \
                    ((((kl) + l4 * 8) * 2) ^ lsw)))

// 9 (WLO) / 6 MFMAs per 32-k chunk: hi*ahi + hi*alo + lo*ahi
#define GSTEP(ahi, alo, ko, L0E, L1E, L2E, I, G, O)                           \
  do {                                                                        \
    bf16x8 wA_ = ld16(whi + off0 + (ko));                                     \
    bf16x8 wB_ = ld16(whi + off1 + (ko));                                     \
    bf16x8 wC_ = ld16(whi + off2 + (ko));                                     \
    I = MFMA(wA_, (ahi), I, 0, 0, 0);                                         \
    G = MFMA(wB_, (ahi), G, 0, 0, 0);                                         \
    O = MFMA(wC_, (ahi), O, 0, 0, 0);                                         \
    I = MFMA(wA_, (alo), I, 0, 0, 0);                                         \
    G = MFMA(wB_, (alo), G, 0, 0, 0);                                         \
    O = MFMA(wC_, (alo), O, 0, 0, 0);                                         \
    if constexpr (WLO) {                                                      \
      bf16x8 lA_ = (L0E), lB_ = (L1E), lC_ = (L2E);                           \
      I = MFMA(lA_, (ahi), I, 0, 0, 0);                                       \
      G = MFMA(lB_, (ahi), G, 0, 0, 0);                                       \
      O = MFMA(lC_, (ahi), O, 0, 0, 0);                                       \
    }                                                                         \
  } while (0)

// chunk with activation from h planes, lo from LDS
#define HSTEP_L(hiP, loP, ka, ko, I, G, O)                                    \
  do {                                                                        \
    bf16x8 ahi_ = ldcoh((hiP) + (ka));                                        \
    bf16x8 alo_ = ldcoh((loP) + (ka));                                        \
    GSTEP(ahi_, alo_, (ko), LD_LO(0, (ko)), LD_LO(1, (ko)), LD_LO(2, (ko)),   \
          I, G, O);                                                           \
  } while (0)

// chunk with activation from h planes, lo streamed from global (L1 K-tail)
#define HSTEP_G(hiP, loP, ka, ko, I, G, O)                                    \
  do {                                                                        \
    bf16x8 ahi_ = ldcoh((hiP) + (ka));                                        \
    bf16x8 alo_ = ldcoh((loP) + (ka));                                        \
    GSTEP(ahi_, alo_, (ko), ld16(wlo + off0 + (ko)),                          \
          ld16(wlo + off1 + (ko)), ld16(wlo + off2 + (ko)), I, G, O);         \
  } while (0)

template <bool WLO>
__global__ __launch_bounds__(512, 2) void lstm_persist(
    const float* __restrict__ xf,
    const float* __restrict__ fw, const float* __restrict__ tw, const float* __restrict__ mag,
    const unsigned short* __restrict__ w0h, const unsigned short* __restrict__ w0l,
    const float* __restrict__ b0,
    const unsigned short* __restrict__ w1h, const unsigned short* __restrict__ w1l,
    const float* __restrict__ b1,
    float* __restrict__ out,
    unsigned short* __restrict__ h0hi, unsigned short* __restrict__ h0lo,
    unsigned short* __restrict__ h1hi, unsigned short* __restrict__ h1lo,
    float* __restrict__ c0, float* __restrict__ c1,
    int* __restrict__ slots, int* __restrict__ go) {
  extern __shared__ char lds[];
  f32x4* red = reinterpret_cast<f32x4*>(lds + LO_BYTES);

  const int tid = threadIdx.x;
  const int lane = tid & 63;
  const int wv = tid >> 6;               // 0..7
  const int mt = wv & 3;                 // row subtile (16 rows)
  const int kh = wv >> 2;                // K-half
  const int l15 = lane & 15, l4 = lane >> 4;
  const int lsw = (l15 & 7) << 4;        // LDS XOR swizzle

  const int wg = blockIdx.x;
  const int layer = wg >> 7;
  const int i = wg & 127;
  const int x8 = i & 7, kk = i >> 3;     // x8 ~ XCD (empirical round-robin)
  const int jt = x8 * 8 + (kk >> 1);     // 0..63
  const int mg = kk & 1;
  const int jb = jt * 16;

  const int bact = mg * 64 + mt * 16 + l15;   // batch row
  const int j0 = jb + l4 * 4;

  const int K = layer ? K1 : K0;
  const unsigned short* whi = layer ? w1h : w0h;
  const unsigned short* wlo = layer ? w1l : w0l;
  const size_t off0 = (size_t)(0 * Hh + jb + l15) * K + l4 * 8;
  const size_t off1 = (size_t)(1 * Hh + jb + l15) * K + l4 * 8;
  const size_t off2 = (size_t)(2 * Hh + jb + l15) * K + l4 * 8;

  const float* bb = layer ? b1 : b0;
  const f32x4 bi = *(const f32x4*)(bb + j0);
  const f32x4 bg = *(const f32x4*)(bb + Hh + j0);
  const f32x4 bo = *(const f32x4*)(bb + 2 * Hh + j0);

  float* cst = (layer ? c1 : c0) + (size_t)bact * Hh + j0;
  float* outb = out + (size_t)bact * Ss * Hh + j0;
  const float emag = __expf(mag[0]);

  // ---- prologue: load W-lo slice into LDS (XOR-swizzled) ----
  if constexpr (WLO) {
    const u64* wsl = (const u64*)wlo;
    const int K4 = K >> 2;               // u64 per full W row
    for (int idx = tid; idx < 48 * 384; idx += 512) {
      int R = idx / 384;                 // 0..47 = g*16 + rr
      int o = idx - R * 384;             // u64 within row (K < 1536 part)
      int g = R >> 4, rr = R & 15;
      u64 v = wsl[(size_t)(g * Hh + jb + rr) * K4 + o];
      *(u64*)(lds + R * LO_ROWB + ((o * 8) ^ ((rr & 7) << 4))) = v;
    }
  }
  __syncthreads();

  for (int p = 0; p < NPH; ++p) {
    const bool act = layer ? (p >= 1) : (p < Ss);
    const int t = layer ? (p - 1) : p;

    f32x4 z = {0.f, 0.f, 0.f, 0.f};
    f32x4 aI0 = z, aG0 = z, aO0 = z, aI1 = z, aG1 = z, aO1 = z;

    if (act) {
      const size_t hbase = (size_t)((p + 1) & 1) * BH + (size_t)bact * Hh + l4 * 8;
      if (layer == 0) {
        if (kh == 0) {
          // x part: k in [0,512), on-the-fly double-bf16
          const float* px = xf + ((size_t)bact * Ss + t) * Ii + l4 * 8;
          const float twm = tw[t] * emag;
#pragma unroll 2
          for (int c = 0; c < 16; ++c) {
            const int k = c * 32;
            f32x4 x0 = *(const f32x4*)(px + k);
            f32x4 x1 = *(const f32x4*)(px + k + 4);
            f32x4 f0 = *(const f32x4*)(fw + k + l4 * 8);
            f32x4 f1 = *(const f32x4*)(fw + k + l4 * 8 + 4);
            x0 *= f0 * twm; x1 *= f1 * twm;
            bf16x8 ahi, alo;
#pragma unroll
            for (int e = 0; e < 4; ++e) {
              unsigned short h0_ = bf16r(x0[e]), h1_ = bf16r(x1[e]);
              ahi[e] = (short)h0_; ahi[e + 4] = (short)h1_;
              alo[e] = (short)bf16r(x0[e] - bf2f(h0_));
              alo[e + 4] = (short)bf16r(x1[e] - bf2f(h1_));
            }
            if (c & 1) GSTEP(ahi, alo, k, LD_LO(0, k), LD_LO(1, k), LD_LO(2, k), aI1, aG1, aO1);
            else       GSTEP(ahi, alo, k, LD_LO(0, k), LD_LO(1, k), LD_LO(2, k), aI0, aG0, aO0);
          }
          // h0_prev: k-offsets [0,256) -> W K [512,768)
          const unsigned short* hp = h0hi + hbase;
          const unsigned short* lp = h0lo + hbase;
#pragma unroll 2
          for (int c = 0; c < 8; c += 2) {
            HSTEP_L(hp, lp, c * 32,       Ii + c * 32,       aI0, aG0, aO0);
            HSTEP_L(hp, lp, (c + 1) * 32, Ii + (c + 1) * 32, aI1, aG1, aO1);
          }
        } else {
          // h0_prev: k-offsets [256,1024) -> W K [768,1536)
          const unsigned short* hp = h0hi + hbase;
          const unsigned short* lp = h0lo + hbase;
#pragma unroll 2
          for (int c = 8; c < 32; c += 2) {
            HSTEP_L(hp, lp, c * 32,       Ii + c * 32,       aI0, aG0, aO0);
            HSTEP_L(hp, lp, (c + 1) * 32, Ii + (c + 1) * 32, aI1, aG1, aO1);
          }
        }
      } else {
        if (kh == 0) {
          // h0_t: W K [0,1024) (all in LDS lo range)
          const unsigned short* hp = h0hi + hbase;
          const unsigned short* lp = h0lo + hbase;
#pragma unroll 2
          for (int c = 0; c < 32; c += 2) {
            HSTEP_L(hp, lp, c * 32,       c * 32,       aI0, aG0, aO0);
            HSTEP_L(hp, lp, (c + 1) * 32, (c + 1) * 32, aI1, aG1, aO1);
          }
        } else {
          // h1_prev: W K [1024,1536) from LDS, [1536,2048) lo from global
          const unsigned short* hp = h1hi + hbase;
          const unsigned short* lp = h1lo + hbase;
#pragma unroll 2
          for (int c = 0; c < 16; c += 2) {
            HSTEP_L(hp, lp, c * 32,       Hh + c * 32,       aI0, aG0, aO0);
            HSTEP_L(hp, lp, (c + 1) * 32, Hh + (c + 1) * 32, aI1, aG1, aO1);
          }
#pragma unroll 2
          for (int c = 16; c < 32; c += 2) {
            HSTEP_G(hp, lp, c * 32,       Hh + c * 32,       aI0, aG0, aO0);
            HSTEP_G(hp, lp, (c + 1) * 32, Hh + (c + 1) * 32, aI1, aG1, aO1);
          }
        }
      }
    }

    if (act && kh == 1) {
      red[((mt * 3 + 0) << 6) + lane] = aI0 + aI1;
      red[((mt * 3 + 1) << 6) + lane] = aG0 + aG1;
      red[((mt * 3 + 2) << 6) + lane] = aO0 + aO1;
    }
    __syncthreads();
    if (act && kh == 0) {
      f32x4 ai = aI0 + aI1 + red[((mt * 3 + 0) << 6) + lane] + bi;
      f32x4 ag = aG0 + aG1 + red[((mt * 3 + 1) << 6) + lane] + bg;
      f32x4 ao = aO0 + aO1 + red[((mt * 3 + 2) << 6) + lane] + bo;
      f32x4 cp = *(const f32x4*)cst;
      f32x4 cn, hn;
      u64 hpk = 0, lpk = 0;
#pragma unroll
      for (int r = 0; r < 4; ++r) {
        float f = sig_(cp[r]);                   // forget gate from c_prev (quirk)
        float cc = f * cp[r] + sig_(ai[r]) * tanh_(ag[r]);
        float hh = sig_(ao[r]) * tanh_(cc) * f;  // extra *f (quirk)
        cn[r] = cc; hn[r] = hh;
        unsigned short hi = bf16r(hh);
        hpk |= (u64)hi << (16 * r);
        lpk |= (u64)bf16r(hh - bf2f(hi)) << (16 * r);
      }
      *(f32x4*)cst = cn;
      const size_t wbase = (size_t)(p & 1) * BH + (size_t)bact * Hh + j0;
      unsigned short* whp = (layer ? h1hi : h0hi) + wbase;
      unsigned short* wlp = (layer ? h1lo : h0lo) + wbase;
      __hip_atomic_store((u64*)whp, hpk, __ATOMIC_RELAXED, __HIP_MEMORY_SCOPE_AGENT);
      __hip_atomic_store((u64*)wlp, lpk, __ATOMIC_RELAXED, __HIP_MEMORY_SCOPE_AGENT);
      if (layer) {
        *(f32x4*)(outb + (size_t)t * Hh) = hn;
        if (t == Ss - 1) {
          *(f32x4*)(out + OF_H1 + (size_t)bact * Hh + j0) = hn;
          *(f32x4*)(out + OF_C1 + (size_t)bact * Hh + j0) = cn;
        }
      } else if (t == Ss - 1) {
        *(f32x4*)(out + OF_H0 + (size_t)bact * Hh + j0) = hn;
        *(f32x4*)(out + OF_C0 + (size_t)bact * Hh + j0) = cn;
      }
    }

    // ---- grid barrier ----
    if (p < NPH - 1) {
      __syncthreads();   // all waves done; vmcnt drained
      if (wg == 0) {
        if (tid == 0)
          __hip_atomic_store(&slots[0], p + 1, __ATOMIC_RELAXED, __HIP_MEMORY_SCOPE_AGENT);
        int gd = 0; bool ok;
        do {
          ok = true;
          if (tid < 256)
            ok = __hip_atomic_load(&slots[tid], __ATOMIC_RELAXED, __HIP_MEMORY_SCOPE_AGENT) > p;
          if (!ok) __builtin_amdgcn_s_sleep(1);
        } while (!__syncthreads_and(ok) && ++gd < (1 << 22));
        if (tid == 0)
          __hip_atomic_store(go, p + 1, __ATOMIC_RELAXED, __HIP_MEMORY_SCOPE_AGENT);
      } else {
        if (tid == 0) {
          __hip_atomic_store(&slots[wg], p + 1, __ATOMIC_RELAXED, __HIP_MEMORY_SCOPE_AGENT);
          int gd = 0;
          while (__hip_atomic_load(go, __ATOMIC_RELAXED, __HIP_MEMORY_SCOPE_AGENT) <= p &&
                 ++gd < (1 << 24))
            __builtin_amdgcn_s_sleep(1);
        }
        __syncthreads();
      }
    }
  }
}

// ---------------------------------------------------------------------------
extern "C" void kernel_launch(void* const* d_in, const int* in_sizes, int n_in,
                              void* d_out, int out_size, void* d_ws, size_t ws_size,
                              hipStream_t stream) {
  const float* x   = (const float*)d_in[0];
  const float* fw  = (const float*)d_in[1];
  const float* tw  = (const float*)d_in[2];
  const float* mag = (const float*)d_in[3];
  const float* W0  = (const float*)d_in[4];
  const float* b0  = (const float*)d_in[5];
  const float* W1  = (const float*)d_in[6];
  const float* b1  = (const float*)d_in[7];
  float* out = (float*)d_out;
  char* ws = (char*)d_ws;

  if (ws_size < WS_HIEND) return;
  const bool wlo = ws_size >= WS_NEED;

  unsigned short* w0h = (unsigned short*)(ws + WS_W0H);
  unsigned short* w1h = (unsigned short*)(ws + WS_W1H);
  unsigned short* w0l = (unsigned short*)(ws + (wlo ? WS_W0L : WS_W0H));
  unsigned short* w1l = (unsigned short*)(ws + (wlo ? WS_W1L : WS_W1H));

  (void)hipFuncSetAttribute((const void*)lstm_persist<true>,
                            hipFuncAttributeMaxDynamicSharedMemorySize, DYN_LDS);
  (void)hipFuncSetAttribute((const void*)lstm_persist<false>,
                            hipFuncAttributeMaxDynamicSharedMemorySize, DYN_LDS);

  k_zero<<<770, 256, 0, stream>>>((uint4*)ws, (int)(WS_ZEND / 16));
  if (wlo)
    k_convert<true><<<1024, 256, 0, stream>>>(W0, W1, w0h, w0l, w1h, w1l);
  else
    k_convert<false><<<1024, 256, 0, stream>>>(W0, W1, w0h, w0l, w1h, w1l);

#define ARGS x, fw, tw, mag, w0h, w0l, b0, w1h, w1l, b1, out,                 \
    (unsigned short*)(ws + WS_H0HI), (unsigned short*)(ws + WS_H0LO),         \
    (unsigned short*)(ws + WS_H1HI), (unsigned short*)(ws + WS_H1LO),         \
    (float*)(ws + WS_C0), (float*)(ws + WS_C1),                               \
    (int*)(ws + WS_SLOTS), (int*)(ws + WS_GO)
  if (wlo)
    lstm_persist<true><<<NWG, 512, DYN_LDS, stream>>>(ARGS);
  else
    lstm_persist<false><<<NWG, 512, DYN_LDS, stream>>>(ARGS);
#undef ARGS
}

// Round 5
// 52477.600 us; speedup vs baseline: 1.4871x; 1.1298x over previous
//
#include <hip/hip_runtime.h>
#include <hip/hip_bf16.h>

// ============================================================================
// 2-layer quirky LSTM, persistent kernel, round 5.
// Numerics (validated r3/r4): double-bf16 (hi+lo) for W, h, x; f32 c.
// r4 lesson: agent-scope (sc1) h loads bypass L2 -> 96MB/phase of LLC-latency
// loads with tiny MLP = 58us/phase. This round h uses NORMAL cached loads;
// cross-XCD coherence via per-phase agent fences (release: buffer_wbl2 ->
// LLC; acquire: buffer_inv -> refill from LLC). L2 then serves the 64x
// cross-WG redundancy. LDS W-lo re-laid chunk-major -> conflict-free b128.
// Barrier: per-phase global counter + go flag (no master WG).
// ============================================================================

typedef __attribute__((ext_vector_type(8))) short bf16x8;
typedef __attribute__((ext_vector_type(4))) float f32x4;
typedef unsigned long long u64;
#define DEV __device__ __forceinline__

namespace {
constexpr int Bb = 128, Ss = 1024, Ii = 512, Hh = 1024;
constexpr int K0 = Ii + Hh;            // 1536
constexpr int K1 = 2 * Hh;             // 2048
constexpr int NWG = 256;               // 1 WG/CU, 512 threads
constexpr int NPH = Ss + 1;

constexpr size_t BH    = (size_t)Bb * Hh;
constexpr size_t OF_H0 = (size_t)Bb * Ss * Hh;
constexpr size_t OF_C0 = OF_H0 + BH;
constexpr size_t OF_H1 = OF_C0 + BH;
constexpr size_t OF_C1 = OF_H1 + BH;

// workspace
constexpr size_t WS_GO    = 0;
constexpr size_t WS_CNT   = 256;                // 1024 ints, per-phase arrive
constexpr size_t WS_C0    = 8192;
constexpr size_t WS_C1    = WS_C0 + BH * 4;
constexpr size_t WS_H0HI  = WS_C1 + BH * 4;     // bf16 [2][B][H] ping-pong
constexpr size_t WS_H0LO  = WS_H0HI + 2 * BH * 2;
constexpr size_t WS_H1HI  = WS_H0LO + 2 * BH * 2;
constexpr size_t WS_H1LO  = WS_H1HI + 2 * BH * 2;
constexpr size_t WS_ZEND  = WS_H1LO + 2 * BH * 2;
constexpr size_t WSZ_W0   = (size_t)3 * Hh * K0 * 2;
constexpr size_t WSZ_W1   = (size_t)3 * Hh * K1 * 2;
constexpr size_t WS_W0H   = WS_ZEND;
constexpr size_t WS_W1H   = WS_W0H + WSZ_W0;
constexpr size_t WS_W0L   = WS_W1H + WSZ_W1;
constexpr size_t WS_W1L   = WS_W0L + WSZ_W0;
constexpr size_t WS_NEED  = WS_W1L + WSZ_W1;    // ~47.2 MB
constexpr size_t WS_HIEND = WS_W0L;             // hi-only fallback

// LDS W-lo, chunk-major: [48 k-chunks][48 rows][64B] -> wave reads 64
// consecutive 16B slots (conflict-free). Then f32x4 reduction buffer.
constexpr int LO_K      = 1536;
constexpr int CHUNKB    = 48 * 64;              // 3072 B per k-chunk
constexpr int LO_BYTES  = 48 * CHUNKB;          // 147456
constexpr int RED_BYTES = 4 * 3 * 64 * 16;      // 12288
constexpr int DYN_LDS   = LO_BYTES + RED_BYTES; // 159744 <= 160 KiB
}

DEV unsigned short bf16r(float f) {
  return __builtin_bit_cast(unsigned short, __float2bfloat16(f));
}
DEV float bf2f(unsigned short u) {
  unsigned int x = (unsigned int)u << 16;
  return __builtin_bit_cast(float, x);
}
DEV float sig_(float x) { return 1.f / (1.f + __expf(-x)); }
DEV float tanh_(float x) {
  float e = __expf(-2.f * fabsf(x));
  return copysignf((1.f - e) / (1.f + e), x);
}
DEV bf16x8 ld16(const unsigned short* p) { return *reinterpret_cast<const bf16x8*>(p); }
#define MFMA __builtin_amdgcn_mfma_f32_16x16x32_bf16

// ---------------------------------------------------------------------------
__global__ void k_zero(uint4* p, int n16) {
  for (int i = blockIdx.x * blockDim.x + threadIdx.x; i < n16; i += gridDim.x * blockDim.x)
    p[i] = make_uint4(0u, 0u, 0u, 0u);
}

template <bool WLO>
__global__ void k_convert(const float* __restrict__ W0, const float* __restrict__ W1,
                          unsigned short* __restrict__ w0h, unsigned short* __restrict__ w0l,
                          unsigned short* __restrict__ w1h, unsigned short* __restrict__ w1l) {
  const long NW04 = (long)3 * Hh * K0 / 4;
  const long NW14 = (long)3 * Hh * K1 / 4;
  const long total = NW04 + NW14;
  for (long i = (long)blockIdx.x * blockDim.x + threadIdx.x; i < total;
       i += (long)gridDim.x * blockDim.x) {
    long e; const float* src; unsigned short *dh, *dl;
    if (i < NW04) { e = i * 4;          src = W0 + e; dh = w0h + e; dl = w0l + e; }
    else          { e = (i - NW04) * 4; src = W1 + e; dh = w1h + e; dl = w1l + e; }
    f32x4 v = *(const f32x4*)src;
    u64 ph = 0, pl = 0;
#pragma unroll
    for (int e2 = 0; e2 < 4; ++e2) {
      unsigned short hi = bf16r(v[e2]);
      ph |= (u64)hi << (16 * e2);
      if (WLO) pl |= (u64)bf16r(v[e2] - bf2f(hi)) << (16 * e2);
    }
    *(u64*)dh = ph;
    if (WLO) *(u64*)dl = pl;
  }
}

// ---------------------------------------------------------------------------
// W-lo fragment from LDS (chunk-major, conflict-free): kl = W K-index < LO_K
#define LD_LO(g, kl)                                                          \
  (*(const bf16x8*)(lds + ((kl) >> 5) * CHUNKB + ((g) * 16 + l15) * 64 + l4 * 16))

// 9 (WLO) / 6 MFMAs per 32-k chunk: hi*ahi + hi*alo + lo*ahi
#define GSTEP(ahi, alo, ko, L0E, L1E, L2E, I, G, O)                           \
  do {                                                                        \
    bf16x8 wA_ = ld16(whi + off0 + (ko));                                     \
    bf16x8 wB_ = ld16(whi + off1 + (ko));                                     \
    bf16x8 wC_ = ld16(whi + off2 + (ko));                                     \
    I = MFMA(wA_, (ahi), I, 0, 0, 0);                                         \
    G = MFMA(wB_, (ahi), G, 0, 0, 0);                                         \
    O = MFMA(wC_, (ahi), O, 0, 0, 0);                                         \
    I = MFMA(wA_, (alo), I, 0, 0, 0);                                         \
    G = MFMA(wB_, (alo), G, 0, 0, 0);                                         \
    O = MFMA(wC_, (alo), O, 0, 0, 0);                                         \
    if constexpr (WLO) {                                                      \
      bf16x8 lA_ = (L0E), lB_ = (L1E), lC_ = (L2E);                           \
      I = MFMA(lA_, (ahi), I, 0, 0, 0);                                       \
      G = MFMA(lB_, (ahi), G, 0, 0, 0);                                       \
      O = MFMA(lC_, (ahi), O, 0, 0, 0);                                       \
    }                                                                         \
  } while (0)

// chunk with activation from h planes (normal cached loads), lo from LDS
#define HSTEP_L(hiP, loP, ka, ko, I, G, O)                                    \
  do {                                                                        \
    bf16x8 ahi_ = ld16((hiP) + (ka));                                         \
    bf16x8 alo_ = ld16((loP) + (ka));                                         \
    GSTEP(ahi_, alo_, (ko), LD_LO(0, (ko)), LD_LO(1, (ko)), LD_LO(2, (ko)),   \
          I, G, O);                                                           \
  } while (0)

// chunk with lo streamed from global (L1 K-tail >= LO_K)
#define HSTEP_G(hiP, loP, ka, ko, I, G, O)                                    \
  do {                                                                        \
    bf16x8 ahi_ = ld16((hiP) + (ka));                                         \
    bf16x8 alo_ = ld16((loP) + (ka));                                         \
    GSTEP(ahi_, alo_, (ko), ld16(wlo + off0 + (ko)),                          \
          ld16(wlo + off1 + (ko)), ld16(wlo + off2 + (ko)), I, G, O);         \
  } while (0)

template <bool WLO>
__global__ __launch_bounds__(512, 2) void lstm_persist(
    const float* __restrict__ xf,
    const float* __restrict__ fw, const float* __restrict__ tw, const float* __restrict__ mag,
    const unsigned short* __restrict__ w0h, const unsigned short* __restrict__ w0l,
    const float* __restrict__ b0,
    const unsigned short* __restrict__ w1h, const unsigned short* __restrict__ w1l,
    const float* __restrict__ b1,
    float* __restrict__ out,
    unsigned short* __restrict__ h0hi, unsigned short* __restrict__ h0lo,
    unsigned short* __restrict__ h1hi, unsigned short* __restrict__ h1lo,
    float* __restrict__ c0, float* __restrict__ c1,
    int* __restrict__ cnt, int* __restrict__ go) {
  extern __shared__ char lds[];
  f32x4* red = reinterpret_cast<f32x4*>(lds + LO_BYTES);

  const int tid = threadIdx.x;
  const int lane = tid & 63;
  const int wv = tid >> 6;               // 0..7
  const int mt = wv & 3;                 // row subtile (16 rows)
  const int kh = wv >> 2;                // K-half
  const int l15 = lane & 15, l4 = lane >> 4;

  const int wg = blockIdx.x;
  const int layer = wg >> 7;
  const int i = wg & 127;
  const int x8 = i & 7, kk = i >> 3;     // x8 ~ XCD (empirical round-robin)
  const int jt = x8 * 8 + (kk >> 1);     // 0..63
  const int mg = kk & 1;
  const int jb = jt * 16;

  const int bact = mg * 64 + mt * 16 + l15;   // batch row
  const int j0 = jb + l4 * 4;

  const int K = layer ? K1 : K0;
  const unsigned short* whi = layer ? w1h : w0h;
  const unsigned short* wlo = layer ? w1l : w0l;
  const size_t off0 = (size_t)(0 * Hh + jb + l15) * K + l4 * 8;
  const size_t off1 = (size_t)(1 * Hh + jb + l15) * K + l4 * 8;
  const size_t off2 = (size_t)(2 * Hh + jb + l15) * K + l4 * 8;

  const float* bb = layer ? b1 : b0;
  const f32x4 bi = *(const f32x4*)(bb + j0);
  const f32x4 bg = *(const f32x4*)(bb + Hh + j0);
  const f32x4 bo = *(const f32x4*)(bb + 2 * Hh + j0);

  float* cst = (layer ? c1 : c0) + (size_t)bact * Hh + j0;
  float* outb = out + (size_t)bact * Ss * Hh + j0;
  const float emag = __expf(mag[0]);

  // ---- prologue: W-lo slice -> LDS, chunk-major [c][48 rows][64B] ----
  if constexpr (WLO) {
    const u64* wsl = (const u64*)wlo;
    const int K4 = K >> 2;
    for (int idx = tid; idx < 48 * 384; idx += 512) {
      int R = idx / 384;                 // 0..47 = g*16 + rr
      int o = idx - R * 384;             // u64 index within row (K < 1536)
      int g = R >> 4, rr = R & 15;
      u64 v = wsl[(size_t)(g * Hh + jb + rr) * K4 + o];
      *(u64*)(lds + (o >> 3) * CHUNKB + R * 64 + (o & 7) * 8) = v;
    }
  }
  __syncthreads();

  for (int p = 0; p < NPH; ++p) {
    const bool act = layer ? (p >= 1) : (p < Ss);
    const int t = layer ? (p - 1) : p;

    if (act) {
      f32x4 z = {0.f, 0.f, 0.f, 0.f};
      f32x4 aI0 = z, aG0 = z, aO0 = z, aI1 = z, aG1 = z, aO1 = z;
      const size_t hbase = (size_t)((p + 1) & 1) * BH + (size_t)bact * Hh + l4 * 8;

      if (layer == 0) {
        if (kh == 0) {
          // x part: k in [0,512), on-the-fly double-bf16
          const float* px = xf + ((size_t)bact * Ss + t) * Ii + l4 * 8;
          const float twm = tw[t] * emag;
#pragma unroll 2
          for (int c = 0; c < 16; ++c) {
            const int k = c * 32;
            f32x4 x0 = *(const f32x4*)(px + k);
            f32x4 x1 = *(const f32x4*)(px + k + 4);
            f32x4 f0 = *(const f32x4*)(fw + k + l4 * 8);
            f32x4 f1 = *(const f32x4*)(fw + k + l4 * 8 + 4);
            x0 *= f0 * twm; x1 *= f1 * twm;
            bf16x8 ahi, alo;
#pragma unroll
            for (int e = 0; e < 4; ++e) {
              unsigned short h0_ = bf16r(x0[e]), h1_ = bf16r(x1[e]);
              ahi[e] = (short)h0_; ahi[e + 4] = (short)h1_;
              alo[e] = (short)bf16r(x0[e] - bf2f(h0_));
              alo[e + 4] = (short)bf16r(x1[e] - bf2f(h1_));
            }
            if (c & 1) GSTEP(ahi, alo, k, LD_LO(0, k), LD_LO(1, k), LD_LO(2, k), aI1, aG1, aO1);
            else       GSTEP(ahi, alo, k, LD_LO(0, k), LD_LO(1, k), LD_LO(2, k), aI0, aG0, aO0);
          }
          // h0_prev: k-offsets [0,256) -> W K [512,768)
          const unsigned short* hp = h0hi + hbase;
          const unsigned short* lp = h0lo + hbase;
#pragma unroll 2
          for (int c = 0; c < 8; c += 2) {
            HSTEP_L(hp, lp, c * 32,       Ii + c * 32,       aI0, aG0, aO0);
            HSTEP_L(hp, lp, (c + 1) * 32, Ii + (c + 1) * 32, aI1, aG1, aO1);
          }
        } else {
          // h0_prev: k-offsets [256,1024) -> W K [768,1536)
          const unsigned short* hp = h0hi + hbase;
          const unsigned short* lp = h0lo + hbase;
#pragma unroll 2
          for (int c = 8; c < 32; c += 2) {
            HSTEP_L(hp, lp, c * 32,       Ii + c * 32,       aI0, aG0, aO0);
            HSTEP_L(hp, lp, (c + 1) * 32, Ii + (c + 1) * 32, aI1, aG1, aO1);
          }
        }
      } else {
        if (kh == 0) {
          // h0_t: W K [0,1024)
          const unsigned short* hp = h0hi + hbase;
          const unsigned short* lp = h0lo + hbase;
#pragma unroll 2
          for (int c = 0; c < 32; c += 2) {
            HSTEP_L(hp, lp, c * 32,       c * 32,       aI0, aG0, aO0);
            HSTEP_L(hp, lp, (c + 1) * 32, (c + 1) * 32, aI1, aG1, aO1);
          }
        } else {
          // h1_prev: W K [1024,1536) lo from LDS, [1536,2048) lo from global
          const unsigned short* hp = h1hi + hbase;
          const unsigned short* lp = h1lo + hbase;
#pragma unroll 2
          for (int c = 0; c < 16; c += 2) {
            HSTEP_L(hp, lp, c * 32,       Hh + c * 32,       aI0, aG0, aO0);
            HSTEP_L(hp, lp, (c + 1) * 32, Hh + (c + 1) * 32, aI1, aG1, aO1);
          }
#pragma unroll 2
          for (int c = 16; c < 32; c += 2) {
            HSTEP_G(hp, lp, c * 32,       Hh + c * 32,       aI0, aG0, aO0);
            HSTEP_G(hp, lp, (c + 1) * 32, Hh + (c + 1) * 32, aI1, aG1, aO1);
          }
        }
      }

      if (kh == 1) {
        red[((mt * 3 + 0) << 6) + lane] = aI0 + aI1;
        red[((mt * 3 + 1) << 6) + lane] = aG0 + aG1;
        red[((mt * 3 + 2) << 6) + lane] = aO0 + aO1;
      }
      __syncthreads();
      if (kh == 0) {
        f32x4 ai = aI0 + aI1 + red[((mt * 3 + 0) << 6) + lane] + bi;
        f32x4 ag = aG0 + aG1 + red[((mt * 3 + 1) << 6) + lane] + bg;
        f32x4 ao = aO0 + aO1 + red[((mt * 3 + 2) << 6) + lane] + bo;
        f32x4 cp = *(const f32x4*)cst;
        f32x4 cn, hn;
        u64 hpk = 0, lpk = 0;
#pragma unroll
        for (int r = 0; r < 4; ++r) {
          float f = sig_(cp[r]);                   // forget gate from c_prev (quirk)
          float cc = f * cp[r] + sig_(ai[r]) * tanh_(ag[r]);
          float hh = sig_(ao[r]) * tanh_(cc) * f;  // extra *f (quirk)
          cn[r] = cc; hn[r] = hh;
          unsigned short hi = bf16r(hh);
          hpk |= (u64)hi << (16 * r);
          lpk |= (u64)bf16r(hh - bf2f(hi)) << (16 * r);
        }
        *(f32x4*)cst = cn;
        const size_t wbase = (size_t)(p & 1) * BH + (size_t)bact * Hh + j0;
        *(u64*)((layer ? h1hi : h0hi) + wbase) = hpk;
        *(u64*)((layer ? h1lo : h0lo) + wbase) = lpk;
        if (layer) {
          *(f32x4*)(outb + (size_t)t * Hh) = hn;
          if (t == Ss - 1) {
            *(f32x4*)(out + OF_H1 + (size_t)bact * Hh + j0) = hn;
            *(f32x4*)(out + OF_C1 + (size_t)bact * Hh + j0) = cn;
          }
        } else if (t == Ss - 1) {
          *(f32x4*)(out + OF_H0 + (size_t)bact * Hh + j0) = hn;
          *(f32x4*)(out + OF_C0 + (size_t)bact * Hh + j0) = cn;
        }
      }
    }

    // ---- grid barrier with cross-XCD coherence fences ----
    if (p < NPH - 1) {
      __syncthreads();   // all waves' stores drained to L2 (vmcnt 0)
      if (tid == 0) {
        __builtin_amdgcn_fence(__ATOMIC_RELEASE, "agent");   // wbl2 -> LLC
        int prev = __hip_atomic_fetch_add(&cnt[p], 1, __ATOMIC_RELAXED,
                                          __HIP_MEMORY_SCOPE_AGENT);
        if (prev == NWG - 1) {
          __hip_atomic_store(go, p + 1, __ATOMIC_RELAXED, __HIP_MEMORY_SCOPE_AGENT);
        } else {
          int gd = 0;
          while (__hip_atomic_load(go, __ATOMIC_RELAXED, __HIP_MEMORY_SCOPE_AGENT) <= p &&
                 ++gd < (1 << 24))
            __builtin_amdgcn_s_sleep(2);
        }
        __builtin_amdgcn_fence(__ATOMIC_ACQUIRE, "agent");   // inv L1+L2
      }
      __syncthreads();
    }
  }
}

// ---------------------------------------------------------------------------
extern "C" void kernel_launch(void* const* d_in, const int* in_sizes, int n_in,
                              void* d_out, int out_size, void* d_ws, size_t ws_size,
                              hipStream_t stream) {
  const float* x   = (const float*)d_in[0];
  const float* fw  = (const float*)d_in[1];
  const float* tw  = (const float*)d_in[2];
  const float* mag = (const float*)d_in[3];
  const float* W0  = (const float*)d_in[4];
  const float* b0  = (const float*)d_in[5];
  const float* W1  = (const float*)d_in[6];
  const float* b1  = (const float*)d_in[7];
  float* out = (float*)d_out;
  char* ws = (char*)d_ws;

  if (ws_size < WS_HIEND) return;
  const bool wlo = ws_size >= WS_NEED;

  unsigned short* w0h = (unsigned short*)(ws + WS_W0H);
  unsigned short* w1h = (unsigned short*)(ws + WS_W1H);
  unsigned short* w0l = (unsigned short*)(ws + (wlo ? WS_W0L : WS_W0H));
  unsigned short* w1l = (unsigned short*)(ws + (wlo ? WS_W1L : WS_W1H));

  (void)hipFuncSetAttribute((const void*)lstm_persist<true>,
                            hipFuncAttributeMaxDynamicSharedMemorySize, DYN_LDS);
  (void)hipFuncSetAttribute((const void*)lstm_persist<false>,
                            hipFuncAttributeMaxDynamicSharedMemorySize, DYN_LDS);

  k_zero<<<770, 256, 0, stream>>>((uint4*)ws, (int)(WS_ZEND / 16));
  if (wlo)
    k_convert<true><<<1024, 256, 0, stream>>>(W0, W1, w0h, w0l, w1h, w1l);
  else
    k_convert<false><<<1024, 256, 0, stream>>>(W0, W1, w0h, w0l, w1h, w1l);

#define ARGS x, fw, tw, mag, w0h, w0l, b0, w1h, w1l, b1, out,                 \
    (unsigned short*)(ws + WS_H0HI), (unsigned short*)(ws + WS_H0LO),         \
    (unsigned short*)(ws + WS_H1HI), (unsigned short*)(ws + WS_H1LO),         \
    (float*)(ws + WS_C0), (float*)(ws + WS_C1),                               \
    (int*)(ws + WS_CNT), (int*)(ws + WS_GO)
  if (wlo)
    lstm_persist<true><<<NWG, 512, DYN_LDS, stream>>>(ARGS);
  else
    lstm_persist<false><<<NWG, 512, DYN_LDS, stream>>>(ARGS);
#undef ARGS
}

// Round 6
// 44843.567 us; speedup vs baseline: 1.7402x; 1.1702x over previous
//
#include <hip/hip_runtime.h>
#include <hip/hip_bf16.h>

// ============================================================================
// 2-layer quirky LSTM, persistent kernel, round 6.
// Numerics (validated r3+): double-bf16 (hi+lo) for W, h, x; f32 c.
// r5 lesson: per-phase acquire-inv wiped L2 -> full W-hi refetch every phase
// (15MB/phase HBM = the 50us wall). This round:
//  - h ring depth 16: producers sc1 write-through stores (LLC), consumers
//    PLAIN cached loads (L2 serves the 16-32x cross-WG redundancy).
//  - acquire-inv fence only every 16 phases (stale window = ring depth).
//  - barrier: slots[wg] store + master-WG poll + go flag (no RMW pileup),
//    NO per-phase fences.
//  - LDS W-lo layout [chunk][gate][l4][l15]: lane i reads byte i*16 ->
//    conflict-free ds_read_b128 (r4/r5 had 8-way = 6e8 conflict cycles).
// ============================================================================

typedef __attribute__((ext_vector_type(8))) short bf16x8;
typedef __attribute__((ext_vector_type(4))) float f32x4;
typedef unsigned long long u64;
#define DEV __device__ __forceinline__

namespace {
constexpr int Bb = 128, Ss = 1024, Ii = 512, Hh = 1024;
constexpr int K0 = Ii + Hh;            // 1536
constexpr int K1 = 2 * Hh;             // 2048
constexpr int NWG = 256;               // 1 WG/CU, 512 threads
constexpr int NPH = Ss + 1;
constexpr int RING = 16;               // h ring depth (= inv period)

constexpr size_t BH    = (size_t)Bb * Hh;              // 131072
constexpr size_t OF_H0 = (size_t)Bb * Ss * Hh;
constexpr size_t OF_C0 = OF_H0 + BH;
constexpr size_t OF_H1 = OF_C0 + BH;
constexpr size_t OF_C1 = OF_H1 + BH;

// workspace
constexpr size_t WS_GO    = 0;
constexpr size_t WS_SLOTS = 256;                     // 256 ints
constexpr size_t WS_C0    = 4096;                    // f32 [B][H]
constexpr size_t WS_C1    = WS_C0 + BH * 4;
constexpr size_t RINGB    = (size_t)RING * BH * 2;   // 4 MB per plane
constexpr size_t WS_H0HI  = WS_C1 + BH * 4;
constexpr size_t WS_H0LO  = WS_H0HI + RINGB;
constexpr size_t WS_H1HI  = WS_H0LO + RINGB;
constexpr size_t WS_H1LO  = WS_H1HI + RINGB;
constexpr size_t WS_ZEND  = WS_H1LO + RINGB;         // ~17.8 MB zeroed/launch
constexpr size_t WSZ_W0   = (size_t)3 * Hh * K0 * 2;
constexpr size_t WSZ_W1   = (size_t)3 * Hh * K1 * 2;
constexpr size_t WS_W0H   = WS_ZEND;
constexpr size_t WS_W1H   = WS_W0H + WSZ_W0;
constexpr size_t WS_W0L   = WS_W1H + WSZ_W1;
constexpr size_t WS_W1L   = WS_W0L + WSZ_W0;
constexpr size_t WS_NEED  = WS_W1L + WSZ_W1;         // ~59 MB
constexpr size_t WS_HIEND = WS_W0L;                  // hi-only fallback

// LDS W-lo: [48 k-chunks][3 gates][4 l4][16 l15][16B]  (3072 B per chunk)
// wave read: lane (l4*16+l15) -> byte lane*16 within the 1024B gate block.
constexpr int CHUNKB    = 3072;
constexpr int LO_K      = 1536;
constexpr int LO_BYTES  = 48 * CHUNKB;              // 147456
constexpr int RED_BYTES = 4 * 3 * 64 * 16;          // 12288
constexpr int DYN_LDS   = LO_BYTES + RED_BYTES;     // 159744 <= 160 KiB
}

DEV unsigned short bf16r(float f) {
  return __builtin_bit_cast(unsigned short, __float2bfloat16(f));
}
DEV float bf2f(unsigned short u) {
  unsigned int x = (unsigned int)u << 16;
  return __builtin_bit_cast(float, x);
}
DEV float sig_(float x) { return 1.f / (1.f + __expf(-x)); }
DEV float tanh_(float x) {
  float e = __expf(-2.f * fabsf(x));
  return copysignf((1.f - e) / (1.f + e), x);
}
DEV bf16x8 ld16(const unsigned short* p) { return *reinterpret_cast<const bf16x8*>(p); }
#define MFMA __builtin_amdgcn_mfma_f32_16x16x32_bf16

// ---------------------------------------------------------------------------
__global__ void k_zero(uint4* p, int n16) {
  for (int i = blockIdx.x * blockDim.x + threadIdx.x; i < n16; i += gridDim.x * blockDim.x)
    p[i] = make_uint4(0u, 0u, 0u, 0u);
}

template <bool WLO>
__global__ void k_convert(const float* __restrict__ W0, const float* __restrict__ W1,
                          unsigned short* __restrict__ w0h, unsigned short* __restrict__ w0l,
                          unsigned short* __restrict__ w1h, unsigned short* __restrict__ w1l) {
  const long NW04 = (long)3 * Hh * K0 / 4;
  const long NW14 = (long)3 * Hh * K1 / 4;
  const long total = NW04 + NW14;
  for (long i = (long)blockIdx.x * blockDim.x + threadIdx.x; i < total;
       i += (long)gridDim.x * blockDim.x) {
    long e; const float* src; unsigned short *dh, *dl;
    if (i < NW04) { e = i * 4;          src = W0 + e; dh = w0h + e; dl = w0l + e; }
    else          { e = (i - NW04) * 4; src = W1 + e; dh = w1h + e; dl = w1l + e; }
    f32x4 v = *(const f32x4*)src;
    u64 ph = 0, pl = 0;
#pragma unroll
    for (int e2 = 0; e2 < 4; ++e2) {
      unsigned short hi = bf16r(v[e2]);
      ph |= (u64)hi << (16 * e2);
      if (WLO) pl |= (u64)bf16r(v[e2] - bf2f(hi)) << (16 * e2);
    }
    *(u64*)dh = ph;
    if (WLO) *(u64*)dl = pl;
  }
}

// ---------------------------------------------------------------------------
// W-lo fragment from LDS (lane-linear layout, conflict-free); kl multiple of 32
#define LD_LO(g, kl)                                                          \
  (*(const bf16x8*)(lds + ((kl) >> 5) * CHUNKB + (g) * 1024 + l4 * 256 + l15 * 16))

// 9 (WLO) / 6 MFMAs per 32-k chunk: hi*ahi + hi*alo + lo*ahi
#define GSTEP(ahi, alo, ko, L0E, L1E, L2E, I, G, O)                           \
  do {                                                                        \
    bf16x8 wA_ = ld16(whi + off0 + (ko));                                     \
    bf16x8 wB_ = ld16(whi + off1 + (ko));                                     \
    bf16x8 wC_ = ld16(whi + off2 + (ko));                                     \
    I = MFMA(wA_, (ahi), I, 0, 0, 0);                                         \
    G = MFMA(wB_, (ahi), G, 0, 0, 0);                                         \
    O = MFMA(wC_, (ahi), O, 0, 0, 0);                                         \
    I = MFMA(wA_, (alo), I, 0, 0, 0);                                         \
    G = MFMA(wB_, (alo), G, 0, 0, 0);                                         \
    O = MFMA(wC_, (alo), O, 0, 0, 0);                                         \
    if constexpr (WLO) {                                                      \
      bf16x8 lA_ = (L0E), lB_ = (L1E), lC_ = (L2E);                           \
      I = MFMA(lA_, (ahi), I, 0, 0, 0);                                       \
      G = MFMA(lB_, (ahi), G, 0, 0, 0);                                       \
      O = MFMA(lC_, (ahi), O, 0, 0, 0);                                       \
    }                                                                         \
  } while (0)

// chunk with activation from h planes (PLAIN cached loads), lo from LDS
#define HSTEP_L(hiP, loP, ka, ko, I, G, O)                                    \
  do {                                                                        \
    bf16x8 ahi_ = ld16((hiP) + (ka));                                         \
    bf16x8 alo_ = ld16((loP) + (ka));                                         \
    GSTEP(ahi_, alo_, (ko), LD_LO(0, (ko)), LD_LO(1, (ko)), LD_LO(2, (ko)),   \
          I, G, O);                                                           \
  } while (0)

// chunk with lo streamed from global (L1 K-tail >= LO_K)
#define HSTEP_G(hiP, loP, ka, ko, I, G, O)                                    \
  do {                                                                        \
    bf16x8 ahi_ = ld16((hiP) + (ka));                                         \
    bf16x8 alo_ = ld16((loP) + (ka));                                         \
    GSTEP(ahi_, alo_, (ko), ld16(wlo + off0 + (ko)),                          \
          ld16(wlo + off1 + (ko)), ld16(wlo + off2 + (ko)), I, G, O);         \
  } while (0)

template <bool WLO>
__global__ __launch_bounds__(512, 2) void lstm_persist(
    const float* __restrict__ xf,
    const float* __restrict__ fw, const float* __restrict__ tw, const float* __restrict__ mag,
    const unsigned short* __restrict__ w0h, const unsigned short* __restrict__ w0l,
    const float* __restrict__ b0,
    const unsigned short* __restrict__ w1h, const unsigned short* __restrict__ w1l,
    const float* __restrict__ b1,
    float* __restrict__ out,
    unsigned short* __restrict__ h0hi, unsigned short* __restrict__ h0lo,
    unsigned short* __restrict__ h1hi, unsigned short* __restrict__ h1lo,
    float* __restrict__ c0, float* __restrict__ c1,
    int* __restrict__ slots, int* __restrict__ go) {
  extern __shared__ char lds[];
  f32x4* red = reinterpret_cast<f32x4*>(lds + LO_BYTES);

  const int tid = threadIdx.x;
  const int lane = tid & 63;
  const int wv = tid >> 6;               // 0..7
  const int mt = wv & 3;                 // row subtile (16 rows)
  const int kh = wv >> 2;                // K-half
  const int l15 = lane & 15, l4 = lane >> 4;

  const int wg = blockIdx.x;
  const int layer = wg >> 7;
  const int i = wg & 127;
  const int x8 = i & 7, kk = i >> 3;     // x8 ~ XCD (wg%8 round-robin)
  const int jt = x8 * 8 + (kk >> 1);     // 0..63
  const int mg = kk & 1;
  const int jb = jt * 16;

  const int bact = mg * 64 + mt * 16 + l15;   // batch row
  const int j0 = jb + l4 * 4;

  const int K = layer ? K1 : K0;
  const unsigned short* whi = layer ? w1h : w0h;
  const unsigned short* wlo = layer ? w1l : w0l;
  const size_t off0 = (size_t)(0 * Hh + jb + l15) * K + l4 * 8;
  const size_t off1 = (size_t)(1 * Hh + jb + l15) * K + l4 * 8;
  const size_t off2 = (size_t)(2 * Hh + jb + l15) * K + l4 * 8;

  const float* bb = layer ? b1 : b0;
  const f32x4 bi = *(const f32x4*)(bb + j0);
  const f32x4 bg = *(const f32x4*)(bb + Hh + j0);
  const f32x4 bo = *(const f32x4*)(bb + 2 * Hh + j0);

  float* cst = (layer ? c1 : c0) + (size_t)bact * Hh + j0;
  float* outb = out + (size_t)bact * Ss * Hh + j0;
  const float emag = __expf(mag[0]);

  // ---- prologue: W-lo slice -> LDS  [c][g][l4][l15][16B] ----
  if constexpr (WLO) {
    const u64* wsl = (const u64*)wlo;
    const int K4 = K >> 2;
    for (int idx = tid; idx < 48 * 384; idx += 512) {
      int R = idx / 384;                 // 0..47 = g*16 + rr
      int o = idx - R * 384;             // u64 index within row (K < 1536)
      int g = R >> 4, rr = R & 15;
      u64 v = wsl[(size_t)(g * Hh + jb + rr) * K4 + o];
      *(u64*)(lds + (o >> 3) * CHUNKB + g * 1024 + ((o >> 1) & 3) * 256 +
              rr * 16 + (o & 1) * 8) = v;
    }
  }
  __syncthreads();

  for (int p = 0; p < NPH; ++p) {
    const bool act = layer ? (p >= 1) : (p < Ss);
    const int t = layer ? (p - 1) : p;
    const int rslot = (p - 1) & (RING - 1);   // read slot (written last phase)
    const int wslot = p & (RING - 1);         // write slot

    if (act) {
      f32x4 z = {0.f, 0.f, 0.f, 0.f};
      f32x4 aI0 = z, aG0 = z, aO0 = z, aI1 = z, aG1 = z, aO1 = z;
      const size_t hbase = (size_t)rslot * BH + (size_t)bact * Hh + l4 * 8;

      if (layer == 0) {
        if (kh == 0) {
          // x part: k in [0,512), on-the-fly double-bf16
          const float* px = xf + ((size_t)bact * Ss + t) * Ii + l4 * 8;
          const float twm = tw[t] * emag;
#pragma unroll 2
          for (int c = 0; c < 16; ++c) {
            const int k = c * 32;
            f32x4 x0 = *(const f32x4*)(px + k);
            f32x4 x1 = *(const f32x4*)(px + k + 4);
            f32x4 f0 = *(const f32x4*)(fw + k + l4 * 8);
            f32x4 f1 = *(const f32x4*)(fw + k + l4 * 8 + 4);
            x0 *= f0 * twm; x1 *= f1 * twm;
            bf16x8 ahi, alo;
#pragma unroll
            for (int e = 0; e < 4; ++e) {
              unsigned short h0_ = bf16r(x0[e]), h1_ = bf16r(x1[e]);
              ahi[e] = (short)h0_; ahi[e + 4] = (short)h1_;
              alo[e] = (short)bf16r(x0[e] - bf2f(h0_));
              alo[e + 4] = (short)bf16r(x1[e] - bf2f(h1_));
            }
            if (c & 1) GSTEP(ahi, alo, k, LD_LO(0, k), LD_LO(1, k), LD_LO(2, k), aI1, aG1, aO1);
            else       GSTEP(ahi, alo, k, LD_LO(0, k), LD_LO(1, k), LD_LO(2, k), aI0, aG0, aO0);
          }
          // h0_prev: k-offsets [0,256) -> W K [512,768)
          const unsigned short* hp = h0hi + hbase;
          const unsigned short* lp = h0lo + hbase;
#pragma unroll 2
          for (int c = 0; c < 8; c += 2) {
            HSTEP_L(hp, lp, c * 32,       Ii + c * 32,       aI0, aG0, aO0);
            HSTEP_L(hp, lp, (c + 1) * 32, Ii + (c + 1) * 32, aI1, aG1, aO1);
          }
        } else {
          // h0_prev: k-offsets [256,1024) -> W K [768,1536)
          const unsigned short* hp = h0hi + hbase;
          const unsigned short* lp = h0lo + hbase;
#pragma unroll 2
          for (int c = 8; c < 32; c += 2) {
            HSTEP_L(hp, lp, c * 32,       Ii + c * 32,       aI0, aG0, aO0);
            HSTEP_L(hp, lp, (c + 1) * 32, Ii + (c + 1) * 32, aI1, aG1, aO1);
          }
        }
      } else {
        if (kh == 0) {
          // h0_t: W K [0,1024)
          const unsigned short* hp = h0hi + hbase;
          const unsigned short* lp = h0lo + hbase;
#pragma unroll 2
          for (int c = 0; c < 32; c += 2) {
            HSTEP_L(hp, lp, c * 32,       c * 32,       aI0, aG0, aO0);
            HSTEP_L(hp, lp, (c + 1) * 32, (c + 1) * 32, aI1, aG1, aO1);
          }
        } else {
          // h1_prev: W K [1024,1536) lo from LDS, [1536,2048) lo from global
          const unsigned short* hp = h1hi + hbase;
          const unsigned short* lp = h1lo + hbase;
#pragma unroll 2
          for (int c = 0; c < 16; c += 2) {
            HSTEP_L(hp, lp, c * 32,       Hh + c * 32,       aI0, aG0, aO0);
            HSTEP_L(hp, lp, (c + 1) * 32, Hh + (c + 1) * 32, aI1, aG1, aO1);
          }
#pragma unroll 2
          for (int c = 16; c < 32; c += 2) {
            HSTEP_G(hp, lp, c * 32,       Hh + c * 32,       aI0, aG0, aO0);
            HSTEP_G(hp, lp, (c + 1) * 32, Hh + (c + 1) * 32, aI1, aG1, aO1);
          }
        }
      }

      if (kh == 1) {
        red[((mt * 3 + 0) << 6) + lane] = aI0 + aI1;
        red[((mt * 3 + 1) << 6) + lane] = aG0 + aG1;
        red[((mt * 3 + 2) << 6) + lane] = aO0 + aO1;
      }
      __syncthreads();
      if (kh == 0) {
        f32x4 ai = aI0 + aI1 + red[((mt * 3 + 0) << 6) + lane] + bi;
        f32x4 ag = aG0 + aG1 + red[((mt * 3 + 1) << 6) + lane] + bg;
        f32x4 ao = aO0 + aO1 + red[((mt * 3 + 2) << 6) + lane] + bo;
        f32x4 cp = *(const f32x4*)cst;
        f32x4 cn, hn;
        u64 hpk = 0, lpk = 0;
#pragma unroll
        for (int r = 0; r < 4; ++r) {
          float f = sig_(cp[r]);                   // forget gate from c_prev (quirk)
          float cc = f * cp[r] + sig_(ai[r]) * tanh_(ag[r]);
          float hh = sig_(ao[r]) * tanh_(cc) * f;  // extra *f (quirk)
          cn[r] = cc; hn[r] = hh;
          unsigned short hi = bf16r(hh);
          hpk |= (u64)hi << (16 * r);
          lpk |= (u64)bf16r(hh - bf2f(hi)) << (16 * r);
        }
        *(f32x4*)cst = cn;
        // sc1 write-through stores -> LLC (consumers first-touch from LLC)
        const size_t wbase = (size_t)wslot * BH + (size_t)bact * Hh + j0;
        __hip_atomic_store((u64*)((layer ? h1hi : h0hi) + wbase), hpk,
                           __ATOMIC_RELAXED, __HIP_MEMORY_SCOPE_AGENT);
        __hip_atomic_store((u64*)((layer ? h1lo : h0lo) + wbase), lpk,
                           __ATOMIC_RELAXED, __HIP_MEMORY_SCOPE_AGENT);
        if (layer) {
          *(f32x4*)(outb + (size_t)t * Hh) = hn;
          if (t == Ss - 1) {
            *(f32x4*)(out + OF_H1 + (size_t)bact * Hh + j0) = hn;
            *(f32x4*)(out + OF_C1 + (size_t)bact * Hh + j0) = cn;
          }
        } else if (t == Ss - 1) {
          *(f32x4*)(out + OF_H0 + (size_t)bact * Hh + j0) = hn;
          *(f32x4*)(out + OF_C0 + (size_t)bact * Hh + j0) = cn;
        }
      }
    }

    // ---- grid barrier (master-WG style, no per-phase fences) ----
    if (p < NPH - 1) {
      __syncthreads();   // compiler drains vmcnt before s_barrier
      if (wg == 0) {
        if (tid == 0)
          __hip_atomic_store(&slots[0], p + 1, __ATOMIC_RELAXED, __HIP_MEMORY_SCOPE_AGENT);
        int gd = 0; bool ok;
        do {
          ok = true;
          if (tid < 256)
            ok = __hip_atomic_load(&slots[tid], __ATOMIC_RELAXED, __HIP_MEMORY_SCOPE_AGENT) > p;
          if (!ok) __builtin_amdgcn_s_sleep(1);
        } while (!__syncthreads_and(ok) && ++gd < (1 << 22));
        if (tid == 0)
          __hip_atomic_store(go, p + 1, __ATOMIC_RELAXED, __HIP_MEMORY_SCOPE_AGENT);
      } else {
        if (tid == 0) {
          __hip_atomic_store(&slots[wg], p + 1, __ATOMIC_RELAXED, __HIP_MEMORY_SCOPE_AGENT);
          int gd = 0;
          while (__hip_atomic_load(go, __ATOMIC_RELAXED, __HIP_MEMORY_SCOPE_AGENT) <= p &&
                 ++gd < (1 << 24))
            __builtin_amdgcn_s_sleep(1);
        }
        __syncthreads();
      }
      // ring-boundary coherence: invalidate L1+L2 once per RING phases so a
      // consumer's cached copy of a ring slot (>= RING phases old) dies
      // before that address is re-read. W-hi refetches from LLC only here.
      if ((p & (RING - 1)) == (RING - 1)) {
        if (tid == 0) __builtin_amdgcn_fence(__ATOMIC_ACQUIRE, "agent");
        __syncthreads();
      }
    }
  }
}

// ---------------------------------------------------------------------------
extern "C" void kernel_launch(void* const* d_in, const int* in_sizes, int n_in,
                              void* d_out, int out_size, void* d_ws, size_t ws_size,
                              hipStream_t stream) {
  const float* x   = (const float*)d_in[0];
  const float* fw  = (const float*)d_in[1];
  const float* tw  = (const float*)d_in[2];
  const float* mag = (const float*)d_in[3];
  const float* W0  = (const float*)d_in[4];
  const float* b0  = (const float*)d_in[5];
  const float* W1  = (const float*)d_in[6];
  const float* b1  = (const float*)d_in[7];
  float* out = (float*)d_out;
  char* ws = (char*)d_ws;

  if (ws_size < WS_HIEND) return;
  const bool wlo = ws_size >= WS_NEED;

  unsigned short* w0h = (unsigned short*)(ws + WS_W0H);
  unsigned short* w1h = (unsigned short*)(ws + WS_W1H);
  unsigned short* w0l = (unsigned short*)(ws + (wlo ? WS_W0L : WS_W0H));
  unsigned short* w1l = (unsigned short*)(ws + (wlo ? WS_W1L : WS_W1H));

  (void)hipFuncSetAttribute((const void*)lstm_persist<true>,
                            hipFuncAttributeMaxDynamicSharedMemorySize, DYN_LDS);
  (void)hipFuncSetAttribute((const void*)lstm_persist<false>,
                            hipFuncAttributeMaxDynamicSharedMemorySize, DYN_LDS);

  k_zero<<<1140, 256, 0, stream>>>((uint4*)ws, (int)(WS_ZEND / 16));
  if (wlo)
    k_convert<true><<<1024, 256, 0, stream>>>(W0, W1, w0h, w0l, w1h, w1l);
  else
    k_convert<false><<<1024, 256, 0, stream>>>(W0, W1, w0h, w0l, w1h, w1l);

#define ARGS x, fw, tw, mag, w0h, w0l, b0, w1h, w1l, b1, out,                 \
    (unsigned short*)(ws + WS_H0HI), (unsigned short*)(ws + WS_H0LO),         \
    (unsigned short*)(ws + WS_H1HI), (unsigned short*)(ws + WS_H1LO),         \
    (float*)(ws + WS_C0), (float*)(ws + WS_C1),                               \
    (int*)(ws + WS_SLOTS), (int*)(ws + WS_GO)
  if (wlo)
    lstm_persist<true><<<NWG, 512, DYN_LDS, stream>>>(ARGS);
  else
    lstm_persist<false><<<NWG, 512, DYN_LDS, stream>>>(ARGS);
#undef ARGS
}